// Round 6
// baseline (285.384 us; speedup 1.0000x reference)
//
#include <hip/hip_runtime.h>
#include <hip/hip_bf16.h>
#include <math.h>

typedef __bf16 bf16;
typedef __bf16 bf16x8 __attribute__((ext_vector_type(8)));
typedef __bf16 bf16x4v __attribute__((ext_vector_type(4)));
typedef short s16x4 __attribute__((ext_vector_type(4)));
typedef float f32x4 __attribute__((ext_vector_type(4)));

#define GLD16(gp, lp) __builtin_amdgcn_global_load_lds( \
    (__attribute__((address_space(1))) void*)(void*)(gp), \
    (__attribute__((address_space(3))) void*)(lp), 16, 0, 0)

#define L_SEQ 2048
#define D_MODEL 2048
#define QKV_N 3072
#define HD 128
#define QSCALE 0.1275310242959836f               // (1/sqrt(128)) * log2(e)
#define LOG2E 1.4426950408889634f

// ---------------------------------------------------------------------------
// prep: fused  (a) x f32->bf16 cast  (b) Wqkv^T cast  (c) Wo^T cast
// ---------------------------------------------------------------------------
__global__ __launch_bounds__(256) void prep(const float* __restrict__ x,
                                            const float* __restrict__ Wqkv,
                                            const float* __restrict__ Wo,
                                            bf16* __restrict__ xb,
                                            bf16* __restrict__ wqkvT,
                                            bf16* __restrict__ woT) {
    __shared__ float tile[32][33];
    int bid = blockIdx.x;
    if (bid < 4096) {                       // cast x (4M elems, 4/thread)
        int idx = (bid * 256 + threadIdx.x) * 4;
        float4 f = *(const float4*)(x + idx);
        bf16x4v o;
        o.x = (bf16)f.x; o.y = (bf16)f.y; o.z = (bf16)f.z; o.w = (bf16)f.w;
        *(bf16x4v*)(xb + idx) = o;
        return;
    }
    bid -= 4096;
    const float* src; bf16* dst; long ld_s, ld_d; int bx, by;
    if (bid < 6144) { bx = bid % 96; by = bid / 96; src = Wqkv; dst = wqkvT; ld_s = QKV_N; ld_d = D_MODEL; }
    else { bid -= 6144; bx = bid & 63; by = bid >> 6; src = Wo; dst = woT; ld_s = D_MODEL; ld_d = D_MODEL; }
    const int tx = threadIdx.x & 31, ty = threadIdx.x >> 5;
    const long c = bx * 32 + tx, r0 = by * 32;
#pragma unroll
    for (int i = 0; i < 4; ++i)
        tile[ty + i * 8][tx] = src[(r0 + ty + i * 8) * ld_s + c];
    __syncthreads();
    const long c0 = bx * 32;
#pragma unroll
    for (int i = 0; i < 4; ++i)
        dst[(c0 + ty + i * 8) * ld_d + r0 + tx] = (bf16)tile[tx][ty + i * 8];
}

// ---------------------------------------------------------------------------
// GEMM1 fused: proj = xb @ WqkvT, RoPE + split + V-transpose epilogue.
// col-tile = one head (Q:0-15, K:16-19, V:20-23).
// ---------------------------------------------------------------------------
__global__ __launch_bounds__(256) void gemm_qkv(const bf16* __restrict__ A,
                                                const bf16* __restrict__ Bt,
                                                bf16* __restrict__ Qb,
                                                bf16* __restrict__ Kb,
                                                bf16* __restrict__ Vtb) {
    constexpr int K = D_MODEL;
    __shared__ __align__(16) bf16 As[128 * 32];
    __shared__ __align__(16) bf16 Bs[128 * 32];
    const int tid = threadIdx.x;
    const int wid = tid >> 6, lane = tid & 63;
    const int quad = lane >> 4, l15 = lane & 15;
    const int wm = wid & 1, wn = wid >> 1;
    const int head = blockIdx.x;
    const long m0 = (long)blockIdx.y * 128, n0 = (long)head * 128;

    const int srow = wid * 32 + (lane >> 2);
    const int scol = ((lane & 3) ^ ((lane >> 3) & 3)) * 8;

    f32x4 acc[4][4];
#pragma unroll
    for (int i = 0; i < 4; ++i)
#pragma unroll
        for (int j = 0; j < 4; ++j) acc[i][j] = (f32x4){0.f, 0.f, 0.f, 0.f};

    const bf16* Ap  = A  + (m0 + srow) * K + scol;
    const bf16* Ap2 = Ap + (long)16 * K;
    const bf16* Bp  = Bt + (n0 + srow) * K + scol;
    const bf16* Bp2 = Bp + (long)16 * K;
    bf16* lA  = &As[(wid * 32) * 32];
    bf16* lA2 = &As[(wid * 32 + 16) * 32];
    bf16* lB  = &Bs[(wid * 32) * 32];
    bf16* lB2 = &Bs[(wid * 32 + 16) * 32];

    const int rsw = ((l15 >> 1) & 3);

    for (int k0 = 0; k0 < K; k0 += 32) {
        GLD16(Ap + k0, lA);
        GLD16(Ap2 + k0, lA2);
        GLD16(Bp + k0, lB);
        GLD16(Bp2 + k0, lB2);
        __syncthreads();
        bf16x8 af[4], bfr[4];
#pragma unroll
        for (int i = 0; i < 4; ++i)
            af[i] = *(const bf16x8*)&As[(wm * 64 + i * 16 + l15) * 32 + (quad ^ rsw) * 8];
#pragma unroll
        for (int j = 0; j < 4; ++j)
            bfr[j] = *(const bf16x8*)&Bs[(j * 32 + wn * 16 + l15) * 32 + (quad ^ rsw) * 8];
#pragma unroll
        for (int i = 0; i < 4; ++i)
#pragma unroll
            for (int j = 0; j < 4; ++j)
                acc[i][j] = __builtin_amdgcn_mfma_f32_16x16x32_bf16(af[i], bfr[j], acc[i][j], 0, 0, 0);
        __syncthreads();
    }

    const int d0 = wn * 16 + l15;                      // 0..31
    if (head < 20) {                                   // Q or K head: RoPE
        const float freq = exp2f((float)d0 * (-10.0f / 31.0f));
        const float sc = head < 16 ? QSCALE : 1.0f;
        bf16* dst = head < 16 ? Qb + (long)head * L_SEQ * HD
                              : Kb + (long)(head - 16) * L_SEQ * HD;
#pragma unroll
        for (int i = 0; i < 4; ++i) {
            const long mb = m0 + wm * 64 + i * 16 + quad * 4;
#pragma unroll
            for (int r = 0; r < 4; ++r) {
                const long row = mb + r;
                float sn, cs;
                sincosf((float)row * freq, &sn, &cs);
                const float x1 = acc[i][0][r], x2 = acc[i][2][r];
                bf16* p = dst + row * HD + d0;
                p[0]  = (bf16)((x1 * cs + x2 * sn) * sc);
                p[64] = (bf16)((x2 * cs - x1 * sn) * sc);
                p[32] = (bf16)(acc[i][1][r] * sc);
                p[96] = (bf16)(acc[i][3][r] * sc);
            }
        }
    } else {                                           // V head: write V^T[d][l]
        bf16* dst = Vtb + (long)(head - 20) * HD * L_SEQ;
#pragma unroll
        for (int i = 0; i < 4; ++i) {
            const long m = m0 + wm * 64 + i * 16 + quad * 4;
#pragma unroll
            for (int j = 0; j < 4; ++j) {
                const int d = j * 32 + d0;
                bf16x4v vv;
#pragma unroll
                for (int r = 0; r < 4; ++r) vv[r] = (bf16)acc[i][j][r];
                *(bf16x4v*)(dst + (long)d * L_SEQ + m) = vv;
            }
        }
    }
}

// ---------------------------------------------------------------------------
// GEMM2 split-K: Cpart[z] = attnb[:, zK/2:(z+1)K/2] @ woT^T slice.
// grid (16,16,2) = 512 blocks -> 2 blocks/CU, barrier stalls overlap.
// ---------------------------------------------------------------------------
__global__ __launch_bounds__(256) void gemm_bt_splitk(const bf16* __restrict__ A,
                                                      const bf16* __restrict__ Bt,
                                                      float* __restrict__ Cp,
                                                      int M, int N, int K) {
    __shared__ __align__(16) bf16 As[128 * 32];
    __shared__ __align__(16) bf16 Bs[128 * 32];
    const int tid = threadIdx.x;
    const int wid = tid >> 6, lane = tid & 63;
    const int quad = lane >> 4, l15 = lane & 15;
    const int wm = wid & 1, wn = wid >> 1;
    const long m0 = (long)blockIdx.y * 128, n0 = (long)blockIdx.x * 128;
    const int kz0 = blockIdx.z * (K >> 1), kz1 = kz0 + (K >> 1);
    float* C = Cp + (long)blockIdx.z * M * N;

    const int srow = wid * 32 + (lane >> 2);
    const int scol = ((lane & 3) ^ ((lane >> 3) & 3)) * 8;

    f32x4 acc[4][4];
#pragma unroll
    for (int i = 0; i < 4; ++i)
#pragma unroll
        for (int j = 0; j < 4; ++j) acc[i][j] = (f32x4){0.f, 0.f, 0.f, 0.f};

    const bf16* Ap  = A  + (m0 + srow) * K + scol;
    const bf16* Ap2 = Ap + (long)16 * K;
    const bf16* Bp  = Bt + (n0 + srow) * K + scol;
    const bf16* Bp2 = Bp + (long)16 * K;
    bf16* lA  = &As[(wid * 32) * 32];
    bf16* lA2 = &As[(wid * 32 + 16) * 32];
    bf16* lB  = &Bs[(wid * 32) * 32];
    bf16* lB2 = &Bs[(wid * 32 + 16) * 32];

    const int rsw = ((l15 >> 1) & 3);

    for (int k0 = kz0; k0 < kz1; k0 += 32) {
        GLD16(Ap + k0, lA);
        GLD16(Ap2 + k0, lA2);
        GLD16(Bp + k0, lB);
        GLD16(Bp2 + k0, lB2);
        __syncthreads();
        bf16x8 af[4], bfr[4];
#pragma unroll
        for (int i = 0; i < 4; ++i)
            af[i] = *(const bf16x8*)&As[(wm * 64 + i * 16 + l15) * 32 + (quad ^ rsw) * 8];
#pragma unroll
        for (int j = 0; j < 4; ++j)
            bfr[j] = *(const bf16x8*)&Bs[(wn * 64 + j * 16 + l15) * 32 + (quad ^ rsw) * 8];
#pragma unroll
        for (int i = 0; i < 4; ++i)
#pragma unroll
            for (int j = 0; j < 4; ++j)
                acc[i][j] = __builtin_amdgcn_mfma_f32_16x16x32_bf16(af[i], bfr[j], acc[i][j], 0, 0, 0);
        __syncthreads();
    }
#pragma unroll
    for (int i = 0; i < 4; ++i)
#pragma unroll
        for (int j = 0; j < 4; ++j) {
            long m = m0 + wm * 64 + i * 16 + quad * 4;
            long n = n0 + wn * 64 + j * 16 + l15;
#pragma unroll
            for (int r = 0; r < 4; ++r)
                C[(m + r) * (long)N + n] = acc[i][j][r];
        }
}

// out = p0 + p1  (streaming f32x4)
__global__ __launch_bounds__(256) void reduce2(const float* __restrict__ p,
                                               float* __restrict__ out, int n) {
    const int idx = (blockIdx.x * 256 + threadIdx.x) * 4;
    if (idx >= n) return;
    f32x4 a = *(const f32x4*)(p + idx);
    f32x4 b = *(const f32x4*)(p + n + idx);
    *(f32x4*)(out + idx) = a + b;
}

// ---------------------------------------------------------------------------
// GQA attention (inverted mask, no-max exp2 softmax, S^T trick).
// K fragments loaded DIRECTLY global->VGPR (K tile is L1/L2-resident;
// kills the structural 8-way LDS conflict of 256B-stride K rows).
// V^T staged via GLD16 (double-buffered; read pattern conflict-free).
// 8 waves = 2 k-split groups x 4; wave owns 32 q-rows; grid 256 = 1 block/CU.
// ---------------------------------------------------------------------------
__global__ __launch_bounds__(512, 2) void attn_kernel(const bf16* __restrict__ Qb,
                                                      const bf16* __restrict__ Kb,
                                                      const bf16* __restrict__ Vtb,
                                                      const float* __restrict__ sink,
                                                      bf16* __restrict__ Ob) {
    __shared__ __align__(1024) char smem[68608];

    const int bid = blockIdx.x;
    const int t  = bid & 15;                 // 128-row q-tile
    const int hq = bid >> 4;
    const int h = hq >> 2;
    const int q0 = t * 128;
    const int tid = threadIdx.x;
    const int wid8 = tid >> 6;
    const int g = wid8 >> 2;                 // k-split group 0/1
    const int w = wid8 & 3;                  // wave in group
    const int lane = tid & 63;
    const int quad = lane >> 4, l15 = lane & 15;

    const bf16* Qg = Qb + (long)hq * L_SEQ * HD;
    const bf16* Kg = Kb + (long)h * L_SEQ * HD;
    const bf16* Vg = Vtb + (long)h * HD * L_SEQ;

    // Q as register B-frags
    bf16x8 qb[2][4];
#pragma unroll
    for (int rf = 0; rf < 2; ++rf)
#pragma unroll
        for (int kkd = 0; kkd < 4; ++kkd)
            qb[rf][kkd] = *(const bf16x8*)(Qg + (long)(q0 + w * 32 + rf * 16 + l15) * HD
                                              + kkd * 32 + quad * 8);

    f32x4 oaccT[2][8];
#pragma unroll
    for (int rf = 0; rf < 2; ++rf)
#pragma unroll
        for (int j = 0; j < 8; ++j) oaccT[rf][j] = (f32x4){0.f, 0.f, 0.f, 0.f};
    float lacc[2] = {0.f, 0.f};

    // valid 64-wide k-tiles: [0, 2t-15] U [2t, 31]
    const int locnt = (2 * t - 14 > 0) ? (2 * t - 14) : 0;
    const int n = locnt + 32 - 2 * t;
    const int iters = (n + 1) >> 1;

    auto stageV = [&](int it2, int buf) {
        const int i = 2 * it2 + g;
        if (i >= n) return;
        const int kt = (i < locnt) ? i : (2 * t + (i - locnt));
        const int k0 = kt * 64;
        bf16* Vtsb = (bf16*)(smem + g * 32768 + buf * 16384);
#pragma unroll
        for (int ii = 0; ii < 4; ++ii) {     // V^T tile: 128 d x 64 keys
            int rowb = w * 32 + ii * 8;
            int row = rowb + (lane >> 3);
            GLD16(Vg + (long)row * L_SEQ + k0 + (((lane & 7) ^ (row & 7)) * 8), &Vtsb[rowb * 64]);
        }
    };

    stageV(0, 0);

    for (int it = 0; it < iters; ++it) {
        __syncthreads();                     // drains stageV(it); prev reads done
        if (it + 1 < iters) stageV(it + 1, (it + 1) & 1);

        const int i = 2 * it + g;
        if (i >= n) continue;
        const int kt = (i < locnt) ? i : (2 * t + (i - locnt));
        const int k0 = kt * 64;
        const bf16* Vts = (const bf16*)(smem + g * 32768 + (it & 1) * 16384);
        const bf16* Kt = Kg + (long)k0 * HD;

        // S^T = K Q^T : per wave 64 keys x 32 q.  K frags from global (L2).
        f32x4 sacc[2][4];
#pragma unroll
        for (int kb = 0; kb < 4; ++kb) {
            bf16x8 ka[4];
#pragma unroll
            for (int kkd = 0; kkd < 4; ++kkd)
                ka[kkd] = *(const bf16x8*)(Kt + (long)(kb * 16 + l15) * HD + kkd * 32 + quad * 8);
#pragma unroll
            for (int rf = 0; rf < 2; ++rf) {
                f32x4 acc = (f32x4){0.f, 0.f, 0.f, 0.f};
#pragma unroll
                for (int kkd = 0; kkd < 4; ++kkd)
                    acc = __builtin_amdgcn_mfma_f32_16x16x32_bf16(ka[kkd], qb[rf][kkd], acc, 0, 0, 0);
                sacc[rf][kb] = acc;
            }
        }

        // mask boundary tiles + exp2 + pack P^T B-frags + l accumulate
        const bool bnd = (kt == 2 * t) || (kt == 2 * t + 1) ||
                         (kt == 2 * t - 15) || (kt == 2 * t - 16);
        s16x4 pb[2][4];
#pragma unroll
        for (int rf = 0; rf < 2; ++rf) {
            const int qq = q0 + w * 32 + rf * 16 + l15;
#pragma unroll
            for (int kb = 0; kb < 4; ++kb) {
#pragma unroll
                for (int r = 0; r < 4; ++r) {
                    float v = sacc[rf][kb][r];
                    if (bnd) {
                        const int kk = k0 + kb * 16 + quad * 4 + r;
                        if (!((kk > qq) || (kk <= qq - 1024))) v = -1e30f;
                    }
                    const float p = exp2f(v);
                    lacc[rf] += p;
                    bf16 hp = (bf16)p;
                    pb[rf][kb][r] = __builtin_bit_cast(short, hp);
                }
            }
        }

        // O^T += V^T P^T : 16x16x16 MFMA, A from LDS (conflict-free), B regs
#pragma unroll
        for (int j = 0; j < 8; ++j) {
            const int drow = j * 16 + l15;
#pragma unroll
            for (int kq = 0; kq < 4; ++kq) {
                const int pc = ((kq * 2 + (quad >> 1)) ^ (l15 & 7));
                s16x4 va = *(const s16x4*)((const char*)&Vts[drow * 64] + pc * 16 + (quad & 1) * 8);
#pragma unroll
                for (int rf = 0; rf < 2; ++rf)
                    oaccT[rf][j] = __builtin_amdgcn_mfma_f32_16x16x16bf16_1k(
                        va, pb[rf][kq], oaccT[rf][j], 0, 0, 0);
            }
        }
    }

    // reduce l across quads
#pragma unroll
    for (int rf = 0; rf < 2; ++rf) {
        lacc[rf] += __shfl_xor(lacc[rf], 16, 64);
        lacc[rf] += __shfl_xor(lacc[rf], 32, 64);
    }

    // ---------------- merge the two groups (simple add) ----------------
    __syncthreads();                      // staging regions now dead
    float* Obuf = (float*)smem;           // [128][132] f32
    float* lbuf = (float*)(smem + 67584); // [128]
    if (g == 1) {
#pragma unroll
        for (int rf = 0; rf < 2; ++rf) {
            const int ql = w * 32 + rf * 16 + l15;
#pragma unroll
            for (int j = 0; j < 8; ++j)
                *(f32x4*)&Obuf[ql * 132 + j * 16 + quad * 4] = oaccT[rf][j];
            if (quad == 0) lbuf[ql] = lacc[rf];
        }
    }
    __syncthreads();
    if (g == 0) {
        const float sv2 = sink[hq] * LOG2E;
#pragma unroll
        for (int rf = 0; rf < 2; ++rf) {
            const int ql = w * 32 + rf * 16 + l15;
            const float ltot = lacc[rf] + lbuf[ql] + exp2f(sv2);
            const float inv = 1.0f / ltot;
            bf16* dst = Ob + (long)(q0 + ql) * D_MODEL + hq * HD;
#pragma unroll
            for (int j = 0; j < 8; ++j) {
                f32x4 o2 = *(const f32x4*)&Obuf[ql * 132 + j * 16 + quad * 4];
                bf16x4v ov;
#pragma unroll
                for (int r = 0; r < 4; ++r)
                    ov[r] = (bf16)((oaccT[rf][j][r] + o2[r]) * inv);
                *(bf16x4v*)(dst + j * 16 + quad * 4) = ov;
            }
        }
    }
}

// ---------------------------------------------------------------------------
extern "C" void kernel_launch(void* const* d_in, const int* in_sizes, int n_in,
                              void* d_out, int out_size, void* d_ws, size_t ws_size,
                              hipStream_t stream) {
    (void)in_sizes; (void)n_in; (void)out_size; (void)ws_size;
    const float* x    = (const float*)d_in[0];
    const float* Wqkv = (const float*)d_in[1];
    const float* Wo   = (const float*)d_in[2];
    const float* s    = (const float*)d_in[3];
    float* out = (float*)d_out;

    // layout: [xb 8M][wqkvT 12.6M][Qb 8M][Kb 2M][Vtb 2M][woT 8M][attnb 8M]
    // gemm2 f32 partials (32M) alias [xb..Vtb] (all dead by then).
    char* ws = (char*)d_ws;
    bf16* xb    = (bf16*)ws;
    bf16* wqkvT = (bf16*)(ws + 8388608);
    bf16* Qb    = (bf16*)(ws + 8388608 + 12582912);
    bf16* Kb    = (bf16*)((char*)Qb + 8388608);
    bf16* Vtb   = (bf16*)((char*)Kb + 2097152);
    bf16* woT   = (bf16*)((char*)Vtb + 2097152);
    bf16* attnb = (bf16*)((char*)woT + 8388608);
    float* part = (float*)ws;                       // 2 x 16 MB, aliases xb..Vtb

    prep<<<14336, 256, 0, stream>>>(x, Wqkv, Wo, xb, wqkvT, woT);

    gemm_qkv<<<dim3(QKV_N / 128, L_SEQ / 128), 256, 0, stream>>>(
        xb, wqkvT, Qb, Kb, Vtb);

    attn_kernel<<<256, 512, 0, stream>>>(Qb, Kb, Vtb, s, attnb);

    gemm_bt_splitk<<<dim3(D_MODEL / 128, L_SEQ / 128, 2), 256, 0, stream>>>(
        attnb, woT, part, L_SEQ, D_MODEL, D_MODEL);

    reduce2<<<(D_MODEL * L_SEQ) / 1024, 256, 0, stream>>>(
        part, out, L_SEQ * D_MODEL);
}

// Round 7
// 232.343 us; speedup vs baseline: 1.2283x; 1.2283x over previous
//
#include <hip/hip_runtime.h>
#include <hip/hip_bf16.h>
#include <math.h>

typedef __bf16 bf16;
typedef __bf16 bf16x8 __attribute__((ext_vector_type(8)));
typedef __bf16 bf16x4v __attribute__((ext_vector_type(4)));
typedef short s16x4 __attribute__((ext_vector_type(4)));
typedef float f32x4 __attribute__((ext_vector_type(4)));

#define GLD16(gp, lp) __builtin_amdgcn_global_load_lds( \
    (__attribute__((address_space(1))) void*)(void*)(gp), \
    (__attribute__((address_space(3))) void*)(lp), 16, 0, 0)

#define L_SEQ 2048
#define D_MODEL 2048
#define QKV_N 3072
#define HD 128
#define QSCALE 0.1275310242959836f               // (1/sqrt(128)) * log2(e)
#define LOG2E 1.4426950408889634f

// ---------------------------------------------------------------------------
// prep: fused  (a) x f32->bf16 cast  (b) Wqkv^T cast  (c) Wo^T cast
// ---------------------------------------------------------------------------
__global__ __launch_bounds__(256) void prep(const float* __restrict__ x,
                                            const float* __restrict__ Wqkv,
                                            const float* __restrict__ Wo,
                                            bf16* __restrict__ xb,
                                            bf16* __restrict__ wqkvT,
                                            bf16* __restrict__ woT) {
    __shared__ float tile[32][33];
    int bid = blockIdx.x;
    if (bid < 4096) {                       // cast x (4M elems, 4/thread)
        int idx = (bid * 256 + threadIdx.x) * 4;
        float4 f = *(const float4*)(x + idx);
        bf16x4v o;
        o.x = (bf16)f.x; o.y = (bf16)f.y; o.z = (bf16)f.z; o.w = (bf16)f.w;
        *(bf16x4v*)(xb + idx) = o;
        return;
    }
    bid -= 4096;
    const float* src; bf16* dst; long ld_s, ld_d; int bx, by;
    if (bid < 6144) { bx = bid % 96; by = bid / 96; src = Wqkv; dst = wqkvT; ld_s = QKV_N; ld_d = D_MODEL; }
    else { bid -= 6144; bx = bid & 63; by = bid >> 6; src = Wo; dst = woT; ld_s = D_MODEL; ld_d = D_MODEL; }
    const int tx = threadIdx.x & 31, ty = threadIdx.x >> 5;
    const long c = bx * 32 + tx, r0 = by * 32;
#pragma unroll
    for (int i = 0; i < 4; ++i)
        tile[ty + i * 8][tx] = src[(r0 + ty + i * 8) * ld_s + c];
    __syncthreads();
    const long c0 = bx * 32;
#pragma unroll
    for (int i = 0; i < 4; ++i)
        dst[(c0 + ty + i * 8) * ld_d + r0 + tx] = (bf16)tile[tx][ty + i * 8];
}

// ---------------------------------------------------------------------------
// 64Mx128N GEMM tile body (BK=32, m97-style staging+swizzle, 8 MFMA/wave/iter,
// 12 KB LDS).  Waves split M (16 rows each); each wave computes 16x128.
// Grid: qkv (24,32)=768 blocks (3/CU), out-proj (16,32)=512 (2/CU) ->
// inter-block overlap hides the barrier vmcnt drain (m114).
// ---------------------------------------------------------------------------
#define GEMM64_BODY(KDIM)                                                        \
    __shared__ __align__(16) bf16 As[64 * 32];                                   \
    __shared__ __align__(16) bf16 Bs[128 * 32];                                  \
    const int tid = threadIdx.x;                                                 \
    const int wid = tid >> 6, lane = tid & 63;                                   \
    const int quad = lane >> 4, l15 = lane & 15;                                 \
    const long m0 = (long)blockIdx.y * 64, n0 = (long)blockIdx.x * 128;          \
    const int srowA = wid * 16 + (lane >> 2);                                    \
    const int srowB = wid * 32 + (lane >> 2);                                    \
    const int scol = ((lane & 3) ^ ((lane >> 3) & 3)) * 8;                       \
    f32x4 acc[8];                                                                \
    _Pragma("unroll")                                                            \
    for (int j = 0; j < 8; ++j) acc[j] = (f32x4){0.f, 0.f, 0.f, 0.f};            \
    const bf16* Ap  = A  + (m0 + srowA) * KDIM + scol;                           \
    const bf16* Bp  = Bt + (n0 + srowB) * KDIM + scol;                           \
    const bf16* Bp2 = Bp + (long)16 * KDIM;                                      \
    bf16* lA  = &As[(wid * 16) * 32];                                            \
    bf16* lB  = &Bs[(wid * 32) * 32];                                            \
    bf16* lB2 = &Bs[(wid * 32 + 16) * 32];                                       \
    const int rsw = ((l15 >> 1) & 3);                                            \
    for (int k0 = 0; k0 < KDIM; k0 += 32) {                                      \
        GLD16(Ap + k0, lA);                                                      \
        GLD16(Bp + k0, lB);                                                      \
        GLD16(Bp2 + k0, lB2);                                                    \
        __syncthreads();                                                         \
        bf16x8 af = *(const bf16x8*)&As[(wid * 16 + l15) * 32 + (quad ^ rsw) * 8]; \
        bf16x8 bfr[8];                                                           \
        _Pragma("unroll")                                                        \
        for (int j = 0; j < 8; ++j)                                              \
            bfr[j] = *(const bf16x8*)&Bs[(j * 16 + l15) * 32 + (quad ^ rsw) * 8]; \
        _Pragma("unroll")                                                        \
        for (int j = 0; j < 8; ++j)                                              \
            acc[j] = __builtin_amdgcn_mfma_f32_16x16x32_bf16(af, bfr[j], acc[j], 0, 0, 0); \
        __syncthreads();                                                         \
    }

// GEMM1 fused: [Q|K|V] = xb @ WqkvT with RoPE/split/V-transpose epilogue.
// blockIdx.x = head (Q:0-15, K:16-19, V:20-23); blockIdx.y = 64-row m-tile.
__global__ __launch_bounds__(256) void gemm_qkv(const bf16* __restrict__ A,
                                                const bf16* __restrict__ Bt,
                                                bf16* __restrict__ Qb,
                                                bf16* __restrict__ Kb,
                                                bf16* __restrict__ Vtb) {
    const int head = blockIdx.x;
    GEMM64_BODY(D_MODEL)

    if (head < 20) {                                   // Q or K head: RoPE
        const float sc = head < 16 ? QSCALE : 1.0f;
        bf16* dst = head < 16 ? Qb + (long)head * L_SEQ * HD
                              : Kb + (long)(head - 16) * L_SEQ * HD;
#pragma unroll
        for (int jj = 0; jj < 2; ++jj) {               // d0 < 32: rotate
            const int d0 = jj * 16 + l15;
            const float freq = exp2f((float)d0 * (-10.0f / 31.0f));
#pragma unroll
            for (int r = 0; r < 4; ++r) {
                const long row = m0 + wid * 16 + quad * 4 + r;
                float sn, cs;
                sincosf((float)row * freq, &sn, &cs);
                const float x1 = acc[jj][r], x2 = acc[jj + 4][r];
                dst[row * HD + d0]      = (bf16)((x1 * cs + x2 * sn) * sc);
                dst[row * HD + d0 + 64] = (bf16)((x2 * cs - x1 * sn) * sc);
            }
        }
#pragma unroll
        for (int jj = 2; jj < 4; ++jj) {               // 32 <= d0 < 64: identity
            const int d0 = jj * 16 + l15;
#pragma unroll
            for (int r = 0; r < 4; ++r) {
                const long row = m0 + wid * 16 + quad * 4 + r;
                dst[row * HD + d0]      = (bf16)(acc[jj][r] * sc);
                dst[row * HD + d0 + 64] = (bf16)(acc[jj + 4][r] * sc);
            }
        }
    } else {                                           // V head: write V^T[d][l]
        bf16* dst = Vtb + (long)(head - 20) * HD * L_SEQ;
        const long m = m0 + wid * 16 + quad * 4;
#pragma unroll
        for (int j = 0; j < 8; ++j) {
            const int d = j * 16 + l15;
            bf16x4v vv;
#pragma unroll
            for (int r = 0; r < 4; ++r) vv[r] = (bf16)acc[j][r];
            *(bf16x4v*)(dst + (long)d * L_SEQ + m) = vv;
        }
    }
}

// GEMM2: out f32 = attnb bf16 @ woT
__global__ __launch_bounds__(256) void gemm_out(const bf16* __restrict__ A,
                                                const bf16* __restrict__ Bt,
                                                float* __restrict__ C) {
    GEMM64_BODY(D_MODEL)
#pragma unroll
    for (int j = 0; j < 8; ++j) {
        const long m = m0 + wid * 16 + quad * 4;
        const long n = n0 + j * 16 + l15;
#pragma unroll
        for (int r = 0; r < 4; ++r)
            C[(m + r) * (long)D_MODEL + n] = acc[j][r];
    }
}

// ---------------------------------------------------------------------------
// GQA attention (R5 version, reverted): inverted mask, no-max exp2 softmax,
// S^T trick, K+V LDS staging (double-buffered), 2 k-split groups x 4 waves.
// ---------------------------------------------------------------------------
__global__ __launch_bounds__(512, 2) void attn_kernel(const bf16* __restrict__ Qb,
                                                      const bf16* __restrict__ Kb,
                                                      const bf16* __restrict__ Vtb,
                                                      const float* __restrict__ sink,
                                                      bf16* __restrict__ Ob) {
    __shared__ __align__(1024) char smem[131072];

    const int bid = blockIdx.x;
    const int t  = bid & 15;                 // 128-row q-tile
    const int hq = bid >> 4;
    const int h = hq >> 2;
    const int q0 = t * 128;
    const int tid = threadIdx.x;
    const int wid8 = tid >> 6;
    const int g = wid8 >> 2;                 // k-split group 0/1
    const int w = wid8 & 3;                  // wave in group
    const int lane = tid & 63;
    const int quad = lane >> 4, l15 = lane & 15;

    const bf16* Qg = Qb + (long)hq * L_SEQ * HD;
    const bf16* Kg = Kb + (long)h * L_SEQ * HD;
    const bf16* Vg = Vtb + (long)h * HD * L_SEQ;

    // Q as register B-frags
    bf16x8 qb[2][4];
#pragma unroll
    for (int rf = 0; rf < 2; ++rf)
#pragma unroll
        for (int kkd = 0; kkd < 4; ++kkd)
            qb[rf][kkd] = *(const bf16x8*)(Qg + (long)(q0 + w * 32 + rf * 16 + l15) * HD
                                              + kkd * 32 + quad * 8);

    f32x4 oaccT[2][8];
#pragma unroll
    for (int rf = 0; rf < 2; ++rf)
#pragma unroll
        for (int j = 0; j < 8; ++j) oaccT[rf][j] = (f32x4){0.f, 0.f, 0.f, 0.f};
    float lacc[2] = {0.f, 0.f};

    // valid 64-wide k-tiles: [0, 2t-15] U [2t, 31]
    const int locnt = (2 * t - 14 > 0) ? (2 * t - 14) : 0;
    const int n = locnt + 32 - 2 * t;
    const int iters = (n + 1) >> 1;

    auto stage = [&](int it2, int buf) {
        const int i = 2 * it2 + g;
        if (i >= n) return;
        const int kt = (i < locnt) ? i : (2 * t + (i - locnt));
        const int k0 = kt * 64;
        bf16* Ksb  = (bf16*)(smem + g * 65536 + buf * 32768);
        bf16* Vtsb = (bf16*)(smem + g * 65536 + buf * 32768 + 16384);
#pragma unroll
        for (int ii = 0; ii < 4; ++ii) {     // K tile: 64 keys x 128 d
            int rowb = w * 16 + ii * 4;
            int row = rowb + quad;
            GLD16(Kg + (long)(k0 + row) * HD + ((l15 ^ (row & 7)) * 8), &Ksb[rowb * 128]);
        }
#pragma unroll
        for (int ii = 0; ii < 4; ++ii) {     // V^T tile: 128 d x 64 keys
            int rowb = w * 32 + ii * 8;
            int row = rowb + (lane >> 3);
            GLD16(Vg + (long)row * L_SEQ + k0 + (((lane & 7) ^ (row & 7)) * 8), &Vtsb[rowb * 64]);
        }
    };

    stage(0, 0);

    for (int it = 0; it < iters; ++it) {
        __syncthreads();                     // drains stage(it); prev reads done
        if (it + 1 < iters) stage(it + 1, (it + 1) & 1);

        const int i = 2 * it + g;
        if (i >= n) continue;
        const int kt = (i < locnt) ? i : (2 * t + (i - locnt));
        const int k0 = kt * 64;
        const bf16* Ks  = (const bf16*)(smem + g * 65536 + (it & 1) * 32768);
        const bf16* Vts = (const bf16*)(smem + g * 65536 + (it & 1) * 32768 + 16384);

        // S^T = K Q^T : per wave 64 keys x 32 q
        f32x4 sacc[2][4];
#pragma unroll
        for (int kb = 0; kb < 4; ++kb) {
            bf16x8 ka[4];
#pragma unroll
            for (int kkd = 0; kkd < 4; ++kkd)
                ka[kkd] = *(const bf16x8*)&Ks[(kb * 16 + l15) * 128 +
                                              (((kkd * 4 + quad) ^ (l15 & 7)) * 8)];
#pragma unroll
            for (int rf = 0; rf < 2; ++rf) {
                f32x4 acc = (f32x4){0.f, 0.f, 0.f, 0.f};
#pragma unroll
                for (int kkd = 0; kkd < 4; ++kkd)
                    acc = __builtin_amdgcn_mfma_f32_16x16x32_bf16(ka[kkd], qb[rf][kkd], acc, 0, 0, 0);
                sacc[rf][kb] = acc;
            }
        }

        // mask boundary tiles + exp2 + pack P^T B-frags + l accumulate
        const bool bnd = (kt == 2 * t) || (kt == 2 * t + 1) ||
                         (kt == 2 * t - 15) || (kt == 2 * t - 16);
        s16x4 pb[2][4];
#pragma unroll
        for (int rf = 0; rf < 2; ++rf) {
            const int qq = q0 + w * 32 + rf * 16 + l15;
#pragma unroll
            for (int kb = 0; kb < 4; ++kb) {
#pragma unroll
                for (int r = 0; r < 4; ++r) {
                    float v = sacc[rf][kb][r];
                    if (bnd) {
                        const int kk = k0 + kb * 16 + quad * 4 + r;
                        if (!((kk > qq) || (kk <= qq - 1024))) v = -1e30f;
                    }
                    const float p = exp2f(v);
                    lacc[rf] += p;
                    bf16 hp = (bf16)p;
                    pb[rf][kb][r] = __builtin_bit_cast(short, hp);
                }
            }
        }

        // O^T += V^T P^T : 16x16x16 MFMA, A from LDS, B from registers
#pragma unroll
        for (int j = 0; j < 8; ++j) {
            const int drow = j * 16 + l15;
#pragma unroll
            for (int kq = 0; kq < 4; ++kq) {
                const int pc = ((kq * 2 + (quad >> 1)) ^ (l15 & 7));
                s16x4 va = *(const s16x4*)((const char*)&Vts[drow * 64] + pc * 16 + (quad & 1) * 8);
#pragma unroll
                for (int rf = 0; rf < 2; ++rf)
                    oaccT[rf][j] = __builtin_amdgcn_mfma_f32_16x16x16bf16_1k(
                        va, pb[rf][kq], oaccT[rf][j], 0, 0, 0);
            }
        }
    }

    // reduce l across quads
#pragma unroll
    for (int rf = 0; rf < 2; ++rf) {
        lacc[rf] += __shfl_xor(lacc[rf], 16, 64);
        lacc[rf] += __shfl_xor(lacc[rf], 32, 64);
    }

    // ---------------- merge the two groups (simple add) ----------------
    __syncthreads();                      // staging regions now dead
    float* Obuf = (float*)smem;           // [128][132] f32
    float* lbuf = (float*)(smem + 67584); // [128]
    if (g == 1) {
#pragma unroll
        for (int rf = 0; rf < 2; ++rf) {
            const int ql = w * 32 + rf * 16 + l15;
#pragma unroll
            for (int j = 0; j < 8; ++j)
                *(f32x4*)&Obuf[ql * 132 + j * 16 + quad * 4] = oaccT[rf][j];
            if (quad == 0) lbuf[ql] = lacc[rf];
        }
    }
    __syncthreads();
    if (g == 0) {
        const float sv2 = sink[hq] * LOG2E;
#pragma unroll
        for (int rf = 0; rf < 2; ++rf) {
            const int ql = w * 32 + rf * 16 + l15;
            const float ltot = lacc[rf] + lbuf[ql] + exp2f(sv2);
            const float inv = 1.0f / ltot;
            bf16* dst = Ob + (long)(q0 + ql) * D_MODEL + hq * HD;
#pragma unroll
            for (int j = 0; j < 8; ++j) {
                f32x4 o2 = *(const f32x4*)&Obuf[ql * 132 + j * 16 + quad * 4];
                bf16x4v ov;
#pragma unroll
                for (int r = 0; r < 4; ++r)
                    ov[r] = (bf16)((oaccT[rf][j][r] + o2[r]) * inv);
                *(bf16x4v*)(dst + j * 16 + quad * 4) = ov;
            }
        }
    }
}

// ---------------------------------------------------------------------------
extern "C" void kernel_launch(void* const* d_in, const int* in_sizes, int n_in,
                              void* d_out, int out_size, void* d_ws, size_t ws_size,
                              hipStream_t stream) {
    (void)in_sizes; (void)n_in; (void)out_size; (void)ws_size;
    const float* x    = (const float*)d_in[0];
    const float* Wqkv = (const float*)d_in[1];
    const float* Wo   = (const float*)d_in[2];
    const float* s    = (const float*)d_in[3];
    float* out = (float*)d_out;

    char* ws = (char*)d_ws;
    bf16* xb    = (bf16*)ws;  ws += (size_t)D_MODEL * D_MODEL * 2;
    bf16* wqkvT = (bf16*)ws;  ws += (size_t)QKV_N * D_MODEL * 2;
    bf16* woT   = (bf16*)ws;  ws += (size_t)D_MODEL * D_MODEL * 2;
    bf16* Qb    = (bf16*)ws;  ws += (size_t)16 * L_SEQ * HD * 2;
    bf16* Kb    = (bf16*)ws;  ws += (size_t)4 * L_SEQ * HD * 2;
    bf16* Vtb   = (bf16*)ws;  ws += (size_t)4 * HD * L_SEQ * 2;
    bf16* attnb = (bf16*)ws;  ws += (size_t)L_SEQ * D_MODEL * 2;

    prep<<<14336, 256, 0, stream>>>(x, Wqkv, Wo, xb, wqkvT, woT);

    gemm_qkv<<<dim3(QKV_N / 128, L_SEQ / 64), 256, 0, stream>>>(
        xb, wqkvT, Qb, Kb, Vtb);

    attn_kernel<<<256, 512, 0, stream>>>(Qb, Kb, Vtb, s, attnb);

    gemm_out<<<dim3(D_MODEL / 128, L_SEQ / 64), 256, 0, stream>>>(
        attnb, woT, out);
}

// Round 8
// 224.654 us; speedup vs baseline: 1.2703x; 1.0342x over previous
//
#include <hip/hip_runtime.h>
#include <hip/hip_bf16.h>
#include <math.h>

typedef __bf16 bf16;
typedef __bf16 bf16x8 __attribute__((ext_vector_type(8)));
typedef __bf16 bf16x4v __attribute__((ext_vector_type(4)));
typedef short s16x4 __attribute__((ext_vector_type(4)));
typedef float f32x4 __attribute__((ext_vector_type(4)));

#define GLD16(gp, lp) __builtin_amdgcn_global_load_lds( \
    (__attribute__((address_space(1))) void*)(void*)(gp), \
    (__attribute__((address_space(3))) void*)(lp), 16, 0, 0)

#define L_SEQ 2048
#define D_MODEL 2048
#define QKV_N 3072
#define HD 128
#define QSCALE 0.1275310242959836f               // (1/sqrt(128)) * log2(e)
#define LOG2E 1.4426950408889634f

// ---------------------------------------------------------------------------
// prep: fused  (a) x f32->bf16 cast  (b) Wqkv^T cast  (c) Wo^T cast
// ---------------------------------------------------------------------------
__global__ __launch_bounds__(256) void prep(const float* __restrict__ x,
                                            const float* __restrict__ Wqkv,
                                            const float* __restrict__ Wo,
                                            bf16* __restrict__ xb,
                                            bf16* __restrict__ wqkvT,
                                            bf16* __restrict__ woT) {
    __shared__ float tile[32][33];
    int bid = blockIdx.x;
    if (bid < 4096) {                       // cast x (4M elems, 4/thread)
        int idx = (bid * 256 + threadIdx.x) * 4;
        float4 f = *(const float4*)(x + idx);
        bf16x4v o;
        o.x = (bf16)f.x; o.y = (bf16)f.y; o.z = (bf16)f.z; o.w = (bf16)f.w;
        *(bf16x4v*)(xb + idx) = o;
        return;
    }
    bid -= 4096;
    const float* src; bf16* dst; long ld_s, ld_d; int bx, by;
    if (bid < 6144) { bx = bid % 96; by = bid / 96; src = Wqkv; dst = wqkvT; ld_s = QKV_N; ld_d = D_MODEL; }
    else { bid -= 6144; bx = bid & 63; by = bid >> 6; src = Wo; dst = woT; ld_s = D_MODEL; ld_d = D_MODEL; }
    const int tx = threadIdx.x & 31, ty = threadIdx.x >> 5;
    const long c = bx * 32 + tx, r0 = by * 32;
#pragma unroll
    for (int i = 0; i < 4; ++i)
        tile[ty + i * 8][tx] = src[(r0 + ty + i * 8) * ld_s + c];
    __syncthreads();
    const long c0 = bx * 32;
#pragma unroll
    for (int i = 0; i < 4; ++i)
        dst[(c0 + ty + i * 8) * ld_d + r0 + tx] = (bf16)tile[tx][ty + i * 8];
}

// ---------------------------------------------------------------------------
// 64Mx128N GEMM tile body (BK=32, staging+swizzle, 8 MFMA/wave/iter).
// ---------------------------------------------------------------------------
#define GEMM64_BODY(KDIM)                                                        \
    __shared__ __align__(16) bf16 As[64 * 32];                                   \
    __shared__ __align__(16) bf16 Bs[128 * 32];                                  \
    const int tid = threadIdx.x;                                                 \
    const int wid = tid >> 6, lane = tid & 63;                                   \
    const int quad = lane >> 4, l15 = lane & 15;                                 \
    const long m0 = (long)blockIdx.y * 64, n0 = (long)blockIdx.x * 128;          \
    const int srowA = wid * 16 + (lane >> 2);                                    \
    const int srowB = wid * 32 + (lane >> 2);                                    \
    const int scol = ((lane & 3) ^ ((lane >> 3) & 3)) * 8;                       \
    f32x4 acc[8];                                                                \
    _Pragma("unroll")                                                            \
    for (int j = 0; j < 8; ++j) acc[j] = (f32x4){0.f, 0.f, 0.f, 0.f};            \
    const bf16* Ap  = A  + (m0 + srowA) * KDIM + scol;                           \
    const bf16* Bp  = Bt + (n0 + srowB) * KDIM + scol;                           \
    const bf16* Bp2 = Bp + (long)16 * KDIM;                                      \
    bf16* lA  = &As[(wid * 16) * 32];                                            \
    bf16* lB  = &Bs[(wid * 32) * 32];                                            \
    bf16* lB2 = &Bs[(wid * 32 + 16) * 32];                                       \
    const int rsw = ((l15 >> 1) & 3);                                            \
    for (int k0 = 0; k0 < KDIM; k0 += 32) {                                      \
        GLD16(Ap + k0, lA);                                                      \
        GLD16(Bp + k0, lB);                                                      \
        GLD16(Bp2 + k0, lB2);                                                    \
        __syncthreads();                                                         \
        bf16x8 af = *(const bf16x8*)&As[(wid * 16 + l15) * 32 + (quad ^ rsw) * 8]; \
        bf16x8 bfr[8];                                                           \
        _Pragma("unroll")                                                        \
        for (int j = 0; j < 8; ++j)                                              \
            bfr[j] = *(const bf16x8*)&Bs[(j * 16 + l15) * 32 + (quad ^ rsw) * 8]; \
        _Pragma("unroll")                                                        \
        for (int j = 0; j < 8; ++j)                                              \
            acc[j] = __builtin_amdgcn_mfma_f32_16x16x32_bf16(af, bfr[j], acc[j], 0, 0, 0); \
        __syncthreads();                                                         \
    }

// GEMM1 fused: [Q|K|V] = xb @ WqkvT with RoPE/split/V-transpose epilogue.
__global__ __launch_bounds__(256) void gemm_qkv(const bf16* __restrict__ A,
                                                const bf16* __restrict__ Bt,
                                                bf16* __restrict__ Qb,
                                                bf16* __restrict__ Kb,
                                                bf16* __restrict__ Vtb) {
    const int head = blockIdx.x;
    GEMM64_BODY(D_MODEL)

    if (head < 20) {                                   // Q or K head: RoPE
        const float sc = head < 16 ? QSCALE : 1.0f;
        bf16* dst = head < 16 ? Qb + (long)head * L_SEQ * HD
                              : Kb + (long)(head - 16) * L_SEQ * HD;
#pragma unroll
        for (int jj = 0; jj < 2; ++jj) {               // d0 < 32: rotate
            const int d0 = jj * 16 + l15;
            const float freq = exp2f((float)d0 * (-10.0f / 31.0f));
#pragma unroll
            for (int r = 0; r < 4; ++r) {
                const long row = m0 + wid * 16 + quad * 4 + r;
                float sn, cs;
                sincosf((float)row * freq, &sn, &cs);
                const float x1 = acc[jj][r], x2 = acc[jj + 4][r];
                dst[row * HD + d0]      = (bf16)((x1 * cs + x2 * sn) * sc);
                dst[row * HD + d0 + 64] = (bf16)((x2 * cs - x1 * sn) * sc);
            }
        }
#pragma unroll
        for (int jj = 2; jj < 4; ++jj) {               // 32 <= d0 < 64: identity
            const int d0 = jj * 16 + l15;
#pragma unroll
            for (int r = 0; r < 4; ++r) {
                const long row = m0 + wid * 16 + quad * 4 + r;
                dst[row * HD + d0]      = (bf16)(acc[jj][r] * sc);
                dst[row * HD + d0 + 64] = (bf16)(acc[jj + 4][r] * sc);
            }
        }
    } else {                                           // V head: write V^T[d][l]
        bf16* dst = Vtb + (long)(head - 20) * HD * L_SEQ;
        const long m = m0 + wid * 16 + quad * 4;
#pragma unroll
        for (int j = 0; j < 8; ++j) {
            const int d = j * 16 + l15;
            bf16x4v vv;
#pragma unroll
            for (int r = 0; r < 4; ++r) vv[r] = (bf16)acc[j][r];
            *(bf16x4v*)(dst + (long)d * L_SEQ + m) = vv;
        }
    }
}

// GEMM2: out f32 = attnb bf16 @ woT
__global__ __launch_bounds__(256) void gemm_out(const bf16* __restrict__ A,
                                                const bf16* __restrict__ Bt,
                                                float* __restrict__ C) {
    GEMM64_BODY(D_MODEL)
#pragma unroll
    for (int j = 0; j < 8; ++j) {
        const long m = m0 + wid * 16 + quad * 4;
        const long n = n0 + j * 16 + l15;
#pragma unroll
        for (int r = 0; r < 4; ++r)
            C[(m + r) * (long)D_MODEL + n] = acc[j][r];
    }
}

// ---------------------------------------------------------------------------
// GQA attention half-job kernel.  Each (hq, t) q-tile's valid k-tile list is
// split into two alternating halves run by independent 256-thread blocks
// (grid 512 = 2 blocks/CU).  Heavy halves (t<8) dispatch first so each CU
// pairs one heavy + one light block.  Writes bf16 O-partials + f32 l-partials;
// attn_combine merges.  Inner loop: S^T = K Q^T trick, no-max exp2 softmax,
// double-buffered K/V staging (64 KB LDS).
// ---------------------------------------------------------------------------
__global__ __launch_bounds__(256, 2) void attn_p(const bf16* __restrict__ Qb,
                                                 const bf16* __restrict__ Kb,
                                                 const bf16* __restrict__ Vtb,
                                                 bf16* __restrict__ Opart,
                                                 float* __restrict__ lpart) {
    __shared__ __align__(1024) char smem[65536];

    const int bid = blockIdx.x;
    int t, hq, half;
    if (bid < 256) { t = bid >> 5; hq = (bid & 31) >> 1; half = bid & 1; }
    else { int b2 = bid - 256; t = 8 + (b2 >> 5); hq = (b2 & 31) >> 1; half = b2 & 1; }
    const int h = hq >> 2;
    const int q0 = t * 128;
    const int tid = threadIdx.x;
    const int w = tid >> 6;                  // wave 0..3, owns q rows w*32..+31
    const int lane = tid & 63;
    const int quad = lane >> 4, l15 = lane & 15;

    const bf16* Qg = Qb + (long)hq * L_SEQ * HD;
    const bf16* Kg = Kb + (long)h * L_SEQ * HD;
    const bf16* Vg = Vtb + (long)h * HD * L_SEQ;

    // Q as register B-frags
    bf16x8 qb[2][4];
#pragma unroll
    for (int rf = 0; rf < 2; ++rf)
#pragma unroll
        for (int kkd = 0; kkd < 4; ++kkd)
            qb[rf][kkd] = *(const bf16x8*)(Qg + (long)(q0 + w * 32 + rf * 16 + l15) * HD
                                              + kkd * 32 + quad * 8);

    f32x4 oaccT[2][8];
#pragma unroll
    for (int rf = 0; rf < 2; ++rf)
#pragma unroll
        for (int j = 0; j < 8; ++j) oaccT[rf][j] = (f32x4){0.f, 0.f, 0.f, 0.f};
    float lacc[2] = {0.f, 0.f};

    // valid 64-wide k-tiles: [0, locnt) U [2t, 32); n always even
    const int locnt = (2 * t - 14 > 0) ? (2 * t - 14) : 0;
    const int n = locnt + 32 - 2 * t;
    const int cnt = n >> 1;                  // this half-job's tile count

    auto ktile = [&](int idx) {
        const int i = 2 * idx + half;
        return (i < locnt) ? i : (2 * t + (i - locnt));
    };

    auto stage = [&](int idx, int buf) {
        const int k0 = ktile(idx) * 64;
        bf16* Ksb  = (bf16*)(smem + buf * 32768);
        bf16* Vtsb = (bf16*)(smem + buf * 32768 + 16384);
#pragma unroll
        for (int ii = 0; ii < 4; ++ii) {     // K tile: 64 keys x 128 d
            int rowb = w * 16 + ii * 4;
            int row = rowb + quad;
            GLD16(Kg + (long)(k0 + row) * HD + ((l15 ^ (row & 7)) * 8), &Ksb[rowb * 128]);
        }
#pragma unroll
        for (int ii = 0; ii < 4; ++ii) {     // V^T tile: 128 d x 64 keys
            int rowb = w * 32 + ii * 8;
            int row = rowb + (lane >> 3);
            GLD16(Vg + (long)row * L_SEQ + k0 + (((lane & 7) ^ (row & 7)) * 8), &Vtsb[rowb * 64]);
        }
    };

    stage(0, 0);

    for (int it = 0; it < cnt; ++it) {
        __syncthreads();                     // drains stage(it); prev reads done
        if (it + 1 < cnt) stage(it + 1, (it + 1) & 1);

        const int kt = ktile(it);
        const int k0 = kt * 64;
        const bf16* Ks  = (const bf16*)(smem + (it & 1) * 32768);
        const bf16* Vts = (const bf16*)(smem + (it & 1) * 32768 + 16384);

        // S^T = K Q^T : per wave 64 keys x 32 q
        f32x4 sacc[2][4];
#pragma unroll
        for (int kb = 0; kb < 4; ++kb) {
            bf16x8 ka[4];
#pragma unroll
            for (int kkd = 0; kkd < 4; ++kkd)
                ka[kkd] = *(const bf16x8*)&Ks[(kb * 16 + l15) * 128 +
                                              (((kkd * 4 + quad) ^ (l15 & 7)) * 8)];
#pragma unroll
            for (int rf = 0; rf < 2; ++rf) {
                f32x4 acc = (f32x4){0.f, 0.f, 0.f, 0.f};
#pragma unroll
                for (int kkd = 0; kkd < 4; ++kkd)
                    acc = __builtin_amdgcn_mfma_f32_16x16x32_bf16(ka[kkd], qb[rf][kkd], acc, 0, 0, 0);
                sacc[rf][kb] = acc;
            }
        }

        // mask boundary tiles + exp2 + pack P^T B-frags + l accumulate
        const bool bnd = (kt == 2 * t) || (kt == 2 * t + 1) ||
                         (kt == 2 * t - 15) || (kt == 2 * t - 16);
        s16x4 pb[2][4];
#pragma unroll
        for (int rf = 0; rf < 2; ++rf) {
            const int qq = q0 + w * 32 + rf * 16 + l15;
#pragma unroll
            for (int kb = 0; kb < 4; ++kb) {
#pragma unroll
                for (int r = 0; r < 4; ++r) {
                    float v = sacc[rf][kb][r];
                    if (bnd) {
                        const int kk = k0 + kb * 16 + quad * 4 + r;
                        if (!((kk > qq) || (kk <= qq - 1024))) v = -1e30f;
                    }
                    const float p = exp2f(v);
                    lacc[rf] += p;
                    bf16 hp = (bf16)p;
                    pb[rf][kb][r] = __builtin_bit_cast(short, hp);
                }
            }
        }

        // O^T += V^T P^T : 16x16x16 MFMA, A from LDS, B from registers
#pragma unroll
        for (int j = 0; j < 8; ++j) {
            const int drow = j * 16 + l15;
#pragma unroll
            for (int kq = 0; kq < 4; ++kq) {
                const int pc = ((kq * 2 + (quad >> 1)) ^ (l15 & 7));
                s16x4 va = *(const s16x4*)((const char*)&Vts[drow * 64] + pc * 16 + (quad & 1) * 8);
#pragma unroll
                for (int rf = 0; rf < 2; ++rf)
                    oaccT[rf][j] = __builtin_amdgcn_mfma_f32_16x16x16bf16_1k(
                        va, pb[rf][kq], oaccT[rf][j], 0, 0, 0);
            }
        }
    }

    // reduce l across quads (keys span quads)
#pragma unroll
    for (int rf = 0; rf < 2; ++rf) {
        lacc[rf] += __shfl_xor(lacc[rf], 16, 64);
        lacc[rf] += __shfl_xor(lacc[rf], 32, 64);
    }

    // write partials: Opart[bid][q 128][d 128] bf16, lpart[bid][q] f32
    bf16* Od = Opart + (long)bid * 16384;
#pragma unroll
    for (int rf = 0; rf < 2; ++rf) {
        const int ql = w * 32 + rf * 16 + l15;
#pragma unroll
        for (int j = 0; j < 8; ++j) {
            bf16x4v ov;
#pragma unroll
            for (int r = 0; r < 4; ++r) ov[r] = (bf16)oaccT[rf][j][r];
            *(bf16x4v*)(Od + ql * 128 + j * 16 + quad * 4) = ov;
        }
        if (quad == 0) lpart[bid * 128 + ql] = lacc[rf];
    }
}

// ---------------------------------------------------------------------------
// combine: attnb[q][hq*128+d] = (O0+O1) / (l0+l1+exp2(sink*log2e))
// grid 2048 = 256 jobs x 8 sub-blocks; 8 elems/thread, fully coalesced.
// ---------------------------------------------------------------------------
__global__ __launch_bounds__(256) void attn_combine(const bf16* __restrict__ Opart,
                                                    const float* __restrict__ lpart,
                                                    const float* __restrict__ sink,
                                                    bf16* __restrict__ attnb) {
    const int job = blockIdx.x >> 3, sub = blockIdx.x & 7;
    const int t = job >> 4, hq = job & 15;
    const int bid0 = (t < 8) ? (t * 32 + hq * 2) : (256 + (t - 8) * 32 + hq * 2);
    const int bid1 = bid0 + 1;
    const int e = sub * 2048 + threadIdx.x * 8;
    const int q = e >> 7, d0 = e & 127;
    bf16x8 o0 = *(const bf16x8*)(Opart + (long)bid0 * 16384 + q * 128 + d0);
    bf16x8 o1 = *(const bf16x8*)(Opart + (long)bid1 * 16384 + q * 128 + d0);
    const float l = lpart[bid0 * 128 + q] + lpart[bid1 * 128 + q] +
                    exp2f(sink[hq] * LOG2E);
    const float inv = 1.0f / l;
    bf16x8 ov;
#pragma unroll
    for (int r = 0; r < 8; ++r)
        ov[r] = (bf16)(((float)o0[r] + (float)o1[r]) * inv);
    *(bf16x8*)(attnb + (long)(t * 128 + q) * D_MODEL + hq * 128 + d0) = ov;
}

// ---------------------------------------------------------------------------
extern "C" void kernel_launch(void* const* d_in, const int* in_sizes, int n_in,
                              void* d_out, int out_size, void* d_ws, size_t ws_size,
                              hipStream_t stream) {
    (void)in_sizes; (void)n_in; (void)out_size; (void)ws_size;
    const float* x    = (const float*)d_in[0];
    const float* Wqkv = (const float*)d_in[1];
    const float* Wo   = (const float*)d_in[2];
    const float* s    = (const float*)d_in[3];
    float* out = (float*)d_out;

    // persistent layout (48 MB): [xb 8M][wqkvT 12.6M][Qb 8M][Kb 2M][Vtb 2M]
    //                            [woT 8M][attnb 8M]
    // Opart (16.8M bf16) + lpart (0.25M) alias [xb..wqkvT] (dead during attn).
    char* ws = (char*)d_ws;
    bf16* xb    = (bf16*)ws;
    bf16* wqkvT = (bf16*)(ws + 8388608);
    bf16* Qb    = (bf16*)(ws + 20971520);
    bf16* Kb    = (bf16*)(ws + 29360128);
    bf16* Vtb   = (bf16*)(ws + 31457280);
    bf16* woT   = (bf16*)(ws + 33554432);
    bf16* attnb = (bf16*)(ws + 41943040);
    bf16* Opart = (bf16*)ws;                  // 512 x 128 x 128 bf16
    float* lpart = (float*)(ws + 16777216);   // 512 x 128 f32

    prep<<<14336, 256, 0, stream>>>(x, Wqkv, Wo, xb, wqkvT, woT);

    gemm_qkv<<<dim3(QKV_N / 128, L_SEQ / 64), 256, 0, stream>>>(
        xb, wqkvT, Qb, Kb, Vtb);

    attn_p<<<512, 256, 0, stream>>>(Qb, Kb, Vtb, Opart, lpart);

    attn_combine<<<2048, 256, 0, stream>>>(Opart, lpart, s, attnb);

    gemm_out<<<dim3(D_MODEL / 128, L_SEQ / 64), 256, 0, stream>>>(
        attnb, woT, out);
}